// Round 12
// baseline (195.996 us; speedup 1.0000x reference)
//
#include <hip/hip_runtime.h>
#include <hip/hip_bf16.h>
#include <cstdint>
#include <cstddef>

typedef __bf16 bf16;
typedef bf16 bf16x4 __attribute__((ext_vector_type(4)));
typedef bf16 bf16x8 __attribute__((ext_vector_type(8)));
typedef float f32x4 __attribute__((ext_vector_type(4)));

#define MFMA_BF16(a,b,c) __builtin_amdgcn_mfma_f32_16x16x32_bf16((a),(b),(c),0,0,0)

typedef __attribute__((address_space(1))) const void gvoid;
typedef __attribute__((address_space(3))) void svoid;
__device__ __forceinline__ void gload16(const bf16* g, bf16* l){
  __builtin_amdgcn_global_load_lds((gvoid*)g, (svoid*)l, 16, 0, 0);
}

// HEAD_COUNTS = [8,6,4,4,6,4] -> boundaries 8,14,18,22,28,32
__device__ __forceinline__ int head_group(int h){
  return (h<8)?0:(h<14)?1:(h<18)?2:(h<22)?3:(h<28)?4:5;
}

// ---------------- fused f32 -> bf16 convert: 6 tensors in one launch ----------------
struct CvtArgs { const float* src[6]; bf16* dst[6]; };
__global__ __launch_bounds__(256) void cvt6_kernel(CvtArgs a, int n){
  const int z = blockIdx.y;
  const float* __restrict__ in = a.src[z];
  bf16* __restrict__ out = a.dst[z];
  int i = (blockIdx.x*256 + threadIdx.x)*8;
  if (i >= n) return;
  const float4* p = (const float4*)(in + i);
  float4 va = p[0], vb = p[1];
  bf16x8 o;
  o[0]=(bf16)va.x; o[1]=(bf16)va.y; o[2]=(bf16)va.z; o[3]=(bf16)va.w;
  o[4]=(bf16)vb.x; o[5]=(bf16)vb.y; o[6]=(bf16)vb.z; o[7]=(bf16)vb.w;
  *(bf16x8*)(out+i) = o;
}

// ---------------- RoPE cos/sin tables: [T][32] f32 ----------------
__global__ __launch_bounds__(256) void rope_tab_kernel(float* __restrict__ cosT,
                                                       float* __restrict__ sinT){
  const int t = blockIdx.x*8 + (threadIdx.x>>5);
  const int i = threadIdx.x&31;
  float invf = powf(10000.0f, -((float)i)/32.0f);
  float ang = (float)t * invf;
  cosT[t*32+i] = cosf(ang);
  sinT[t*32+i] = sinf(ang);
}

// ---------------- GEMM core: acc = A[M,K] * B[N,K]^T, 128x128 tile ----------------
// m97 structure: BK=32, linear LDS, global_load_lds width=16, 2 barriers/K-step.
__device__ __forceinline__ void gemm_core(const bf16* __restrict__ A,
                                          const bf16* __restrict__ B,
                                          int row0, int col0,
                                          f32x4 (&acc)[4][4]){
  __shared__ bf16 As[128*32];
  __shared__ bf16 Bs[128*32];
  const int tid  = threadIdx.x;
  const int wave = tid>>6, lane = tid&63;
  const int l16  = lane&15, lg = lane>>4;
  const int wr   = wave>>1, wc = wave&1;

  const bf16* Ag0 = A + (size_t)(row0 + wave*32      + (lane>>2))*2048 + (lane&3)*8;
  const bf16* Ag1 = A + (size_t)(row0 + wave*32 + 16 + (lane>>2))*2048 + (lane&3)*8;
  const bf16* Bg0 = B + (size_t)(col0 + wave*32      + (lane>>2))*2048 + (lane&3)*8;
  const bf16* Bg1 = B + (size_t)(col0 + wave*32 + 16 + (lane>>2))*2048 + (lane&3)*8;
  bf16* AsB0 = As + (wave*32     )*32;
  bf16* AsB1 = As + (wave*32 + 16)*32;
  bf16* BsB0 = Bs + (wave*32     )*32;
  bf16* BsB1 = Bs + (wave*32 + 16)*32;

  #pragma unroll
  for (int m=0;m<4;++m)
    #pragma unroll
    for (int n=0;n<4;++n)
      #pragma unroll
      for (int r=0;r<4;++r) acc[m][n][r] = 0.f;

  for (int kt=0; kt<64; ++kt){
    const int ko = kt*32;
    gload16(Ag0 + ko, AsB0);
    gload16(Ag1 + ko, AsB1);
    gload16(Bg0 + ko, BsB0);
    gload16(Bg1 + ko, BsB1);
    __syncthreads();
    bf16x8 af[4], bfr[4];
    #pragma unroll
    for (int m=0;m<4;++m) af[m]  = *(const bf16x8*)&As[(wr*64+m*16+l16)*32 + lg*8];
    #pragma unroll
    for (int n=0;n<4;++n) bfr[n] = *(const bf16x8*)&Bs[(wc*64+n*16+l16)*32 + lg*8];
    #pragma unroll
    for (int m=0;m<4;++m)
      #pragma unroll
      for (int n=0;n<4;++n)
        acc[m][n] = MFMA_BF16(af[m], bfr[n], acc[m][n]);
    __syncthreads();
  }
}

// ---------------- QKV GEMM with fused RoPE / relayout / V-transpose epilogues ----------------
__global__ __launch_bounds__(256) void gemm_qkv_kernel(
    const bf16* __restrict__ A,
    const bf16* __restrict__ B0, const bf16* __restrict__ B1, const bf16* __restrict__ B2,
    bf16* __restrict__ Qs, bf16* __restrict__ Ks, bf16* __restrict__ Vt,
    const float* __restrict__ cosT, const float* __restrict__ sinT,
    const float* __restrict__ mw, const float* __restrict__ ts){
  const int z = blockIdx.z;
  const bf16* B = (z==0)?B0:((z==1)?B1:B2);
  const int row0 = blockIdx.y*128, col0 = blockIdx.x*128;

  f32x4 acc[4][4];
  gemm_core(A, B, row0, col0, acc);

  const int tid  = threadIdx.x;
  const int wave = tid>>6, lane = tid&63;
  const int l16  = lane&15, lg = lane>>4;
  const int wr   = wave>>1, wc = wave&1;
  const int h    = (col0 + wc*64) >> 6;      // wave's 64-col span = one head

  if (z == 2){
    // V-transpose epilogue: acc[m][n][0..3] = 4 consecutive t -> one 8B store
    #pragma unroll
    for (int n=0;n<4;++n){
      const int d = n*16 + l16;
      #pragma unroll
      for (int m=0;m<4;++m){
        const int t0 = row0 + wr*64 + m*16 + lg*4;
        bf16x4 v;
        #pragma unroll
        for (int r=0;r<4;++r) v[r] = (bf16)acc[m][n][r];
        *(bf16x4*)&Vt[((size_t)h*64 + d)*2048 + t0] = v;
      }
    }
  } else {
    const float sc = (z==0) ? 0.125f*ts[h]*mw[head_group(h)] : 1.0f;
    bf16* Out = (z==0) ? Qs : Ks;
    #pragma unroll
    for (int m=0;m<4;++m){
      #pragma unroll
      for (int r=0;r<4;++r){
        const int t = row0 + wr*64 + m*16 + lg*4 + r;
        const float* ct = cosT + t*32;
        const float* st = sinT + t*32;
        bf16* dst = Out + ((size_t)h*2048 + t)*64;
        #pragma unroll
        for (int n=0;n<2;++n){
          const int i = n*16 + l16;
          const float c = ct[i], s = st[i];
          const float a1 = acc[m][n][r], a2 = acc[m][n+2][r];
          dst[i]    = (bf16)((a1*c - a2*s)*sc);
          dst[i+32] = (bf16)((a2*c + a1*s)*sc);
        }
      }
    }
  }
}

__global__ __launch_bounds__(256) void gemm_out_kernel(
    const bf16* __restrict__ A, const bf16* __restrict__ B, float* __restrict__ C){
  const int row0 = blockIdx.y*128, col0 = blockIdx.x*128;
  f32x4 acc[4][4];
  gemm_core(A, B, row0, col0, acc);
  const int tid  = threadIdx.x;
  const int wave = tid>>6, lane = tid&63;
  const int l16  = lane&15, lg = lane>>4;
  const int wr   = wave>>1, wc = wave&1;
  #pragma unroll
  for (int m=0;m<4;++m)
    #pragma unroll
    for (int n=0;n<4;++n)
      #pragma unroll
      for (int r=0;r<4;++r){
        size_t idx = (size_t)(row0 + wr*64 + m*16 + lg*4 + r)*2048
                   + col0 + wc*64 + n*16 + l16;
        C[idx] = acc[m][n][r];
      }
}

// ---------------- fused causal attention ----------------
// r8 skeleton (8 waves x 16 q-rows, reg-staged double-buffered swizzled LDS,
// complementary-qt pairing) with SWAPPED QK^T: S' = mfma(K,Q) puts, per lane,
// q = qbase+l16 and k = k0+c*16+lg*4+r. P-writes become 4x ds_write_b64 (packed
// along k) instead of 16x ds_write_b16; PV step and output layout unchanged.
// Bias loads: bf16x4 per c at per-lane row. Row-sum: scalar per lane, reduced
// via shfl_xor(16,32), redistributed with one __shfl per r at the end.
__global__ __launch_bounds__(512) void attn_kernel(
    const bf16* __restrict__ Qs, const bf16* __restrict__ Ks,
    const bf16* __restrict__ Vt, const bf16* __restrict__ biasb,
    const float* __restrict__ mw, bf16* __restrict__ attout){
  const int n  = blockIdx.x;                       // 0..511
  const int h  = ((n>>8)<<4) | ((n>>4)&15);        // 0..31
  const int qt = (n&256) ? (n&15) : 15-(n&15);     // paired: qt(n)+qt(n+256)=15
  const int tid = threadIdx.x, wid = tid>>6, lane = tid&63;
  const int l16 = lane&15, lg = lane>>4;
  const float w_h = mw[head_group(h)];
  const int qbase = qt*128 + wid*16;
  const int qg0 = qbase + lg*4;                    // +r = this lane's OUTPUT q rows
  const int qlane = qbase + l16;                   // this lane's softmax q row
  const int qtop = qbase + 15;
  const int nkt = 2*qt + 2;

  __shared__ bf16 Kl[2][4096];
  __shared__ bf16 Vl[2][4096];
  __shared__ bf16 plds[8][16][80];

  // staging: 512 threads, one b128 per tensor per tile
  const int srow = tid>>3, ssub = tid&7;
  const bf16* Kg = Ks + (size_t)h*2048*64 + srow*64 + ssub*8;   // + k0*64
  const bf16* Vg = Vt + ((size_t)h*64 + srow)*2048 + ssub*8;    // + k0
  const int wsw = srow*64 + ((ssub ^ (srow&7))<<3);

  // Q fragments (registers, whole kernel)
  const bf16* Qp = Qs + ((size_t)h*2048 + qbase + l16)*64 + lg*8;
  bf16x8 qf0 = *(const bf16x8*)Qp;
  bf16x8 qf1 = *(const bf16x8*)(Qp + 32);

  // bias: per-lane row qlane, cols k0 + c*16 + lg*4 (+r)
  const bf16* Bq = biasb + (size_t)qlane*2048 + lg*4;

  f32x4 O[4];
  float lsum = 0.f;
  #pragma unroll
  for (int c=0;c<4;++c)
    #pragma unroll
    for (int r=0;r<4;++r) O[c][r] = 0.f;

  int rK0[4], rK1[4];
  #pragma unroll
  for (int c=0;c<4;++c){
    const int row = c*16 + l16;
    rK0[c] = row*64 + (((lg  ) ^ (row&7))<<3);
    rK1[c] = row*64 + (((4+lg) ^ (row&7))<<3);
  }

  // bias for tile 0, prefetched (w_h and the -4 exp shift folded in)
  float bc[4][4];
  #pragma unroll
  for (int c=0;c<4;++c){
    bf16x4 b4 = *(const bf16x4*)&Bq[c*16];
    #pragma unroll
    for (int r=0;r<4;++r) bc[c][r] = w_h*(float)b4[r] - 4.0f;
  }

  // prologue: stage tile 0
  {
    bf16x8 k0v = *(const bf16x8*)Kg;
    bf16x8 v0v = *(const bf16x8*)Vg;
    *(bf16x8*)&Kl[0][wsw] = k0v;
    *(bf16x8*)&Vl[0][wsw] = v0v;
  }
  __syncthreads();

  int cur = 0;
  for (int kt=0; kt<nkt; ++kt){
    const int k0 = kt*64;
    const bool more = (kt+1 < nkt);
    bf16x8 kA, vA;
    float bn[4][4];
    const bool needb = more && (k0+64 <= qtop);
    if (more){
      kA = *(const bf16x8*)(Kg + (size_t)(k0+64)*64);
      vA = *(const bf16x8*)(Vg + (k0+64));
    }
    if (needb){
      #pragma unroll
      for (int c=0;c<4;++c){
        bf16x4 b4 = *(const bf16x4*)&Bq[(k0+64) + c*16];
        #pragma unroll
        for (int r=0;r<4;++r) bn[c][r] = w_h*(float)b4[r] - 4.0f;
      }
    }

    if (k0 <= qtop){                       // wave-uniform skip of fully-masked tiles
      // S' init = prefetched (w*bias - 4); S'[c] rowgrp r -> k = k0+c*16+lg*4+r
      f32x4 S[4];
      #pragma unroll
      for (int c=0;c<4;++c)
        #pragma unroll
        for (int r=0;r<4;++r) S[c][r] = bc[c][r];

      // S' += K Q^T from LDS (swapped operands: A=K rows, B=Q rows)
      __builtin_amdgcn_s_setprio(1);
      #pragma unroll
      for (int c=0;c<4;++c){
        bf16x8 kf0 = *(const bf16x8*)&Kl[cur][rK0[c]];
        bf16x8 kf1 = *(const bf16x8*)&Kl[cur][rK1[c]];
        S[c] = MFMA_BF16(kf0, qf0, S[c]);
        S[c] = MFMA_BF16(kf1, qf1, S[c]);
      }
      __builtin_amdgcn_s_setprio(0);

      // exp; per-element causal mask only when the tile crosses the diagonal
      if (k0 + 63 > qbase){
        #pragma unroll
        for (int c=0;c<4;++c){
          const int kb_ = k0 + c*16 + lg*4;
          #pragma unroll
          for (int r=0;r<4;++r){
            float p = __expf(S[c][r]);
            if (kb_ + r > qlane) p = 0.f;
            S[c][r] = p; lsum += p;
          }
        }
      } else {
        #pragma unroll
        for (int c=0;c<4;++c)
          #pragma unroll
          for (int r=0;r<4;++r){
            const float p = __expf(S[c][r]);
            S[c][r] = p; lsum += p;
          }
      }

      // P -> per-wave LDS: packed b64 writes (r runs along k)
      #pragma unroll
      for (int c=0;c<4;++c){
        bf16x4 p4;
        #pragma unroll
        for (int r=0;r<4;++r) p4[r] = (bf16)S[c][r];
        *(bf16x4*)&plds[wid][l16][c*16 + lg*4] = p4;
      }
      bf16x8 pf0 = *(const bf16x8*)&plds[wid][l16][lg*8];
      bf16x8 pf1 = *(const bf16x8*)&plds[wid][l16][32 + lg*8];

      // O += P * V from LDS (unchanged; output layout identical to r8)
      __builtin_amdgcn_s_setprio(1);
      #pragma unroll
      for (int c=0;c<4;++c){
        bf16x8 vf0 = *(const bf16x8*)&Vl[cur][rK0[c]];
        bf16x8 vf1 = *(const bf16x8*)&Vl[cur][rK1[c]];
        O[c] = MFMA_BF16(pf0, vf0, O[c]);
        O[c] = MFMA_BF16(pf1, vf1, O[c]);
      }
      __builtin_amdgcn_s_setprio(0);
    }

    if (more){
      *(bf16x8*)&Kl[cur^1][wsw] = kA;
      *(bf16x8*)&Vl[cur^1][wsw] = vA;
    }
    if (needb){
      #pragma unroll
      for (int c=0;c<4;++c)
        #pragma unroll
        for (int r=0;r<4;++r) bc[c][r] = bn[c][r];
    }
    __syncthreads();
    cur ^= (int)more;
  }

  // row-sum: lanes sharing l16 (lg groups) hold partial sums of row qlane
  lsum += __shfl_xor(lsum, 16);
  lsum += __shfl_xor(lsum, 32);
  // redistribute: output row qg0+r = qbase+lg*4+r lives at lane l16 = lg*4+r
  float linv[4];
  #pragma unroll
  for (int r=0;r<4;++r) linv[r] = 1.0f / __shfl(lsum, lg*4 + r);

  #pragma unroll
  for (int c=0;c<4;++c)
    #pragma unroll
    for (int r=0;r<4;++r)
      attout[(size_t)(qg0+r)*2048 + h*64 + c*16 + l16] = (bf16)(O[c][r]*linv[r]);
}

// ---------------- launcher ----------------
extern "C" void kernel_launch(void* const* d_in, const int* in_sizes, int n_in,
                              void* d_out, int out_size, void* d_ws, size_t ws_size,
                              hipStream_t stream){
  const float* x    = (const float*)d_in[0];
  const float* bias = (const float*)d_in[2];
  const float* mw   = (const float*)d_in[3];
  const float* Wq   = (const float*)d_in[4];
  const float* Wk   = (const float*)d_in[5];
  const float* Wv   = (const float*)d_in[6];
  const float* Wo   = (const float*)d_in[7];
  const float* ts   = (const float*)d_in[8];
  float* out = (float*)d_out;

  const size_t SZ = (size_t)2048*2048;
  bf16* base = (bf16*)d_ws;
  bf16* xb   = base;
  bf16* Wqb  = base + 1*SZ;
  bf16* Wkb  = base + 2*SZ;
  bf16* Wvb  = base + 3*SZ;
  bf16* Wob  = base + 4*SZ;
  bf16* bb   = base + 5*SZ;
  bf16* Qsb  = base + 6*SZ;
  bf16* Ksb  = base + 7*SZ;
  bf16* Vtb  = base + 8*SZ;
  bf16* att  = base + 9*SZ;
  float* cosT = (float*)(base + 10*SZ);
  float* sinT = cosT + 2048*32;

  CvtArgs ca;
  ca.src[0]=x;  ca.src[1]=Wq;  ca.src[2]=Wk;  ca.src[3]=Wv;  ca.src[4]=Wo;  ca.src[5]=bias;
  ca.dst[0]=xb; ca.dst[1]=Wqb; ca.dst[2]=Wkb; ca.dst[3]=Wvb; ca.dst[4]=Wob; ca.dst[5]=bb;
  const int nb = (int)(SZ/8/256);
  cvt6_kernel<<<dim3(nb,6),256,0,stream>>>(ca, (int)SZ);
  rope_tab_kernel<<<256,256,0,stream>>>(cosT, sinT);
  gemm_qkv_kernel<<<dim3(16,16,3),256,0,stream>>>(xb, Wqb,Wkb,Wvb,
                                                  Qsb,Ksb,Vtb, cosT,sinT, mw,ts);
  attn_kernel<<<512,512,0,stream>>>(Qsb,Ksb,Vtb,bb,mw,att);
  gemm_out_kernel<<<dim3(16,16),256,0,stream>>>(att, Wob, out);
}

// Round 13
// 182.020 us; speedup vs baseline: 1.0768x; 1.0768x over previous
//
#include <hip/hip_runtime.h>
#include <hip/hip_bf16.h>
#include <cstdint>
#include <cstddef>

typedef __bf16 bf16;
typedef bf16 bf16x4 __attribute__((ext_vector_type(4)));
typedef bf16 bf16x8 __attribute__((ext_vector_type(8)));
typedef float f32x4 __attribute__((ext_vector_type(4)));

#define MFMA_BF16(a,b,c) __builtin_amdgcn_mfma_f32_16x16x32_bf16((a),(b),(c),0,0,0)

typedef __attribute__((address_space(1))) const void gvoid;
typedef __attribute__((address_space(3))) void svoid;
__device__ __forceinline__ void gload16(const bf16* g, bf16* l){
  __builtin_amdgcn_global_load_lds((gvoid*)g, (svoid*)l, 16, 0, 0);
}

__device__ __forceinline__ void wait_lgkm0(){
  asm volatile("s_waitcnt lgkmcnt(0)" ::: "memory");
  __builtin_amdgcn_sched_barrier(0);
}
template<int N> __device__ __forceinline__ void wait_vm(){
  if constexpr (N==0) asm volatile("s_waitcnt vmcnt(0)" ::: "memory");
  else                asm volatile("s_waitcnt vmcnt(4)" ::: "memory");
  __builtin_amdgcn_sched_barrier(0);
}

// HEAD_COUNTS = [8,6,4,4,6,4] -> boundaries 8,14,18,22,28,32
__device__ __forceinline__ int head_group(int h){
  return (h<8)?0:(h<14)?1:(h<18)?2:(h<22)?3:(h<28)?4:5;
}

// ---------------- fused f32 -> bf16 convert: 6 tensors in one launch ----------------
struct CvtArgs { const float* src[6]; bf16* dst[6]; };
__global__ __launch_bounds__(256) void cvt6_kernel(CvtArgs a, int n){
  const int z = blockIdx.y;
  const float* __restrict__ in = a.src[z];
  bf16* __restrict__ out = a.dst[z];
  int i = (blockIdx.x*256 + threadIdx.x)*8;
  if (i >= n) return;
  const float4* p = (const float4*)(in + i);
  float4 va = p[0], vb = p[1];
  bf16x8 o;
  o[0]=(bf16)va.x; o[1]=(bf16)va.y; o[2]=(bf16)va.z; o[3]=(bf16)va.w;
  o[4]=(bf16)vb.x; o[5]=(bf16)vb.y; o[6]=(bf16)vb.z; o[7]=(bf16)vb.w;
  *(bf16x8*)(out+i) = o;
}

// ---------------- RoPE cos/sin tables: [T][32] f32 ----------------
__global__ __launch_bounds__(256) void rope_tab_kernel(float* __restrict__ cosT,
                                                       float* __restrict__ sinT){
  const int t = blockIdx.x*8 + (threadIdx.x>>5);
  const int i = threadIdx.x&31;
  float invf = powf(10000.0f, -((float)i)/32.0f);
  float ang = (float)t * invf;
  cosT[t*32+i] = cosf(ang);
  sinT[t*32+i] = sinf(ang);
}

// ---------------- QKV GEMM: 256x256 tile, BK=64, 4-phase counted-vmcnt pipeline ----------
// LDS layout per buffer/matrix: two K-planes [ks][256 rows][32 elems], row stride 64B,
// chunk swizzle: LDS[r][c] holds global[r][c ^ ((r>>1)&3)] (write: pre-swizzled global
// source on linear gload_lds; read: same XOR). Raw s_barrier (no implicit vmcnt drain),
// vmcnt(4) at phase-1/3 ends; last K-tile peeled with vmcnt(0).
// 8 waves = 2(M) x 4(N); per-wave output 128x64 (acc[8][4]); wave's 64-col span = head.
__global__ __launch_bounds__(512,2) void gemm_qkv256_kernel(
    const bf16* __restrict__ A,
    const bf16* __restrict__ B0, const bf16* __restrict__ B1, const bf16* __restrict__ B2,
    bf16* __restrict__ Qs, bf16* __restrict__ Ks, bf16* __restrict__ Vt,
    const float* __restrict__ cosT, const float* __restrict__ sinT,
    const float* __restrict__ mw, const float* __restrict__ ts){
  const int z = blockIdx.z;
  const bf16* B = (z==0)?B0:((z==1)?B1:B2);
  const int row0 = blockIdx.y*256, col0 = blockIdx.x*256;

  __shared__ bf16 lds[2][2][2][8192];   // [buf][mat A=0/B=1][ks][256*32]

  const int tid = threadIdx.x, w = tid>>6, lane = tid&63;
  const int l16 = lane&15, lg = lane>>4;
  const int wr = w>>2, wc = w&3;
  const int axor = (l16>>1)&3;

  // staging: lane -> global row w*32 + j*16 + (lane>>2), source chunk (lane&3)^((lane>>3)&3)
  const int grow = w*32 + (lane>>2);
  const int gcol = ((lane&3) ^ ((lane>>3)&3))*8;
  const bf16* Ag = A + (size_t)(row0 + grow)*2048 + gcol;
  const bf16* Bg = B + (size_t)(col0 + grow)*2048 + gcol;

  f32x4 acc[8][4];
  #pragma unroll
  for (int m=0;m<8;++m)
    #pragma unroll
    for (int nn=0;nn<4;++nn)
      #pragma unroll
      for (int r=0;r<4;++r) acc[m][nn][r] = 0.f;

  bf16x8 af[4], bfr[4];

#define STAGE2(MAT, KS, BUF, KT1) \
  { const bf16* gp = ((MAT)? Bg : Ag) + (size_t)(KT1)*64 + (KS)*32;   \
    bf16* lp = (bf16*)&lds[BUF][MAT][KS][w*1024];                      \
    gload16(gp, lp);                                                   \
    gload16(gp + (size_t)16*2048, lp + 512); }

#define LDB4(KS, CB) \
  _Pragma("unroll") for (int nn=0;nn<4;++nn) \
    bfr[nn] = *(const bf16x8*)&lds[CB][1][KS][(wc*64+nn*16+l16)*32 + ((lg^axor)<<3)];
#define LDA4(MG, KS, CB) \
  _Pragma("unroll") for (int i=0;i<4;++i) \
    af[i] = *(const bf16x8*)&lds[CB][0][KS][(wr*128+((MG)*4+i)*16+l16)*32 + ((lg^axor)<<3)];
#define MFMA16(MG) \
  __builtin_amdgcn_s_setprio(1); \
  _Pragma("unroll") for (int i=0;i<4;++i) \
    _Pragma("unroll") for (int nn=0;nn<4;++nn) \
      acc[(MG)*4+i][nn] = MFMA_BF16(af[i], bfr[nn], acc[(MG)*4+i][nn]); \
  __builtin_amdgcn_s_setprio(0);

  // prologue: stage tile 0 into buf 0 (order A0,B0,A1,B1), wait oldest 4
  STAGE2(0,0,0,0)
  STAGE2(1,0,0,0)
  STAGE2(0,1,0,0)
  STAGE2(1,1,0,0)
  wait_vm<4>();
  __builtin_amdgcn_s_barrier();

  for (int kt=0; kt<31; ++kt){
    const int cb = kt&1, nbuf = cb^1;
    // P0: ks0, m0-3; stage A-ks0(t+1)
    LDB4(0, cb)
    LDA4(0, 0, cb)
    STAGE2(0,0,nbuf,kt+1)
    __builtin_amdgcn_s_barrier();
    wait_lgkm0();
    MFMA16(0)
    __builtin_amdgcn_s_barrier();
    // P1: ks0, m4-7; stage B-ks0(t+1); wait ks1(t) staged
    LDA4(1, 0, cb)
    STAGE2(1,0,nbuf,kt+1)
    __builtin_amdgcn_s_barrier();
    wait_lgkm0();
    MFMA16(1)
    wait_vm<4>();
    __builtin_amdgcn_s_barrier();
    // P2: ks1, m0-3; stage A-ks1(t+1)
    LDB4(1, cb)
    LDA4(0, 1, cb)
    STAGE2(0,1,nbuf,kt+1)
    __builtin_amdgcn_s_barrier();
    wait_lgkm0();
    MFMA16(0)
    __builtin_amdgcn_s_barrier();
    // P3: ks1, m4-7; stage B-ks1(t+1); wait ks0(t+1) staged
    LDA4(1, 1, cb)
    STAGE2(1,1,nbuf,kt+1)
    __builtin_amdgcn_s_barrier();
    wait_lgkm0();
    MFMA16(1)
    wait_vm<4>();
    __builtin_amdgcn_s_barrier();
  }
  {
    const int cb = 1;   // 31&1
    LDB4(0, cb)
    LDA4(0, 0, cb)
    __builtin_amdgcn_s_barrier();
    wait_lgkm0();
    MFMA16(0)
    __builtin_amdgcn_s_barrier();
    LDA4(1, 0, cb)
    __builtin_amdgcn_s_barrier();
    wait_lgkm0();
    MFMA16(1)
    wait_vm<0>();
    __builtin_amdgcn_s_barrier();
    LDB4(1, cb)
    LDA4(0, 1, cb)
    __builtin_amdgcn_s_barrier();
    wait_lgkm0();
    MFMA16(0)
    __builtin_amdgcn_s_barrier();
    LDA4(1, 1, cb)
    wait_lgkm0();
    MFMA16(1)
  }
#undef STAGE2
#undef LDB4
#undef LDA4
#undef MFMA16

  // epilogues (wave's 64-col span = one head)
  const int h = blockIdx.x*4 + wc;
  if (z == 2){
    #pragma unroll
    for (int nn=0;nn<4;++nn){
      const int d = nn*16 + l16;
      #pragma unroll
      for (int m=0;m<8;++m){
        const int t0 = row0 + wr*128 + m*16 + lg*4;
        bf16x4 v;
        #pragma unroll
        for (int r=0;r<4;++r) v[r] = (bf16)acc[m][nn][r];
        *(bf16x4*)&Vt[((size_t)h*64 + d)*2048 + t0] = v;
      }
    }
  } else {
    const float sc = (z==0) ? 0.125f*ts[h]*mw[head_group(h)] : 1.0f;
    bf16* Out = (z==0) ? Qs : Ks;
    #pragma unroll
    for (int m=0;m<8;++m){
      #pragma unroll
      for (int r=0;r<4;++r){
        const int t = row0 + wr*128 + m*16 + lg*4 + r;
        const float* ct = cosT + t*32;
        const float* st = sinT + t*32;
        bf16* dst = Out + ((size_t)h*2048 + t)*64;
        #pragma unroll
        for (int nn=0;nn<2;++nn){
          const int i = nn*16 + l16;
          const float c = ct[i], s = st[i];
          const float a1 = acc[m][nn][r], a2 = acc[m][nn+2][r];
          dst[i]    = (bf16)((a1*c - a2*s)*sc);
          dst[i+32] = (bf16)((a2*c + a1*s)*sc);
        }
      }
    }
  }
}

// ---------------- GEMM core (m97 128x128) for the output projection ----------------
__device__ __forceinline__ void gemm_core(const bf16* __restrict__ A,
                                          const bf16* __restrict__ B,
                                          int row0, int col0,
                                          f32x4 (&acc)[4][4]){
  __shared__ bf16 As[128*32];
  __shared__ bf16 Bs[128*32];
  const int tid  = threadIdx.x;
  const int wave = tid>>6, lane = tid&63;
  const int l16  = lane&15, lg = lane>>4;
  const int wr   = wave>>1, wc = wave&1;

  const bf16* Ag0 = A + (size_t)(row0 + wave*32      + (lane>>2))*2048 + (lane&3)*8;
  const bf16* Ag1 = A + (size_t)(row0 + wave*32 + 16 + (lane>>2))*2048 + (lane&3)*8;
  const bf16* Bg0 = B + (size_t)(col0 + wave*32      + (lane>>2))*2048 + (lane&3)*8;
  const bf16* Bg1 = B + (size_t)(col0 + wave*32 + 16 + (lane>>2))*2048 + (lane&3)*8;
  bf16* AsB0 = As + (wave*32     )*32;
  bf16* AsB1 = As + (wave*32 + 16)*32;
  bf16* BsB0 = Bs + (wave*32     )*32;
  bf16* BsB1 = Bs + (wave*32 + 16)*32;

  #pragma unroll
  for (int m=0;m<4;++m)
    #pragma unroll
    for (int n=0;n<4;++n)
      #pragma unroll
      for (int r=0;r<4;++r) acc[m][n][r] = 0.f;

  for (int kt=0; kt<64; ++kt){
    const int ko = kt*32;
    gload16(Ag0 + ko, AsB0);
    gload16(Ag1 + ko, AsB1);
    gload16(Bg0 + ko, BsB0);
    gload16(Bg1 + ko, BsB1);
    __syncthreads();
    bf16x8 af[4], bfr[4];
    #pragma unroll
    for (int m=0;m<4;++m) af[m]  = *(const bf16x8*)&As[(wr*64+m*16+l16)*32 + lg*8];
    #pragma unroll
    for (int n=0;n<4;++n) bfr[n] = *(const bf16x8*)&Bs[(wc*64+n*16+l16)*32 + lg*8];
    #pragma unroll
    for (int m=0;m<4;++m)
      #pragma unroll
      for (int n=0;n<4;++n)
        acc[m][n] = MFMA_BF16(af[m], bfr[n], acc[m][n]);
    __syncthreads();
  }
}

__global__ __launch_bounds__(256) void gemm_out_kernel(
    const bf16* __restrict__ A, const bf16* __restrict__ B, float* __restrict__ C){
  const int row0 = blockIdx.y*128, col0 = blockIdx.x*128;
  f32x4 acc[4][4];
  gemm_core(A, B, row0, col0, acc);
  const int tid  = threadIdx.x;
  const int wave = tid>>6, lane = tid&63;
  const int l16  = lane&15, lg = lane>>4;
  const int wr   = wave>>1, wc = wave&1;
  #pragma unroll
  for (int m=0;m<4;++m)
    #pragma unroll
    for (int n=0;n<4;++n)
      #pragma unroll
      for (int r=0;r<4;++r){
        size_t idx = (size_t)(row0 + wr*64 + m*16 + lg*4 + r)*2048
                   + col0 + wc*64 + n*16 + l16;
        C[idx] = acc[m][n][r];
      }
}

// ---------------- fused causal attention (r8 verbatim: best measured, ~60us) ----------
__global__ __launch_bounds__(512) void attn_kernel(
    const bf16* __restrict__ Qs, const bf16* __restrict__ Ks,
    const bf16* __restrict__ Vt, const bf16* __restrict__ biasb,
    const float* __restrict__ mw, bf16* __restrict__ attout){
  const int n  = blockIdx.x;                       // 0..511
  const int h  = ((n>>8)<<4) | ((n>>4)&15);        // 0..31
  const int qt = (n&256) ? (n&15) : 15-(n&15);     // paired: qt(n)+qt(n+256)=15
  const int tid = threadIdx.x, wid = tid>>6, lane = tid&63;
  const int l16 = lane&15, lg = lane>>4;
  const float w_h = mw[head_group(h)];
  const int qbase = qt*128 + wid*16;
  const int qg0 = qbase + lg*4;                    // +r = this lane's q rows
  const int nkt = 2*qt + 2;

  __shared__ bf16 Kl[2][4096];
  __shared__ bf16 Vl[2][4096];
  __shared__ bf16 plds[8][16][72];

  // staging: 512 threads, one b128 per tensor per tile
  const int srow = tid>>3, ssub = tid&7;
  const bf16* Kg = Ks + (size_t)h*2048*64 + srow*64 + ssub*8;   // + k0*64
  const bf16* Vg = Vt + ((size_t)h*64 + srow)*2048 + ssub*8;    // + k0
  const int wsw = srow*64 + ((ssub ^ (srow&7))<<3);

  // Q fragments (registers, whole kernel)
  const bf16* Qp = Qs + ((size_t)h*2048 + qbase + l16)*64 + lg*8;
  bf16x8 qf0 = *(const bf16x8*)Qp;
  bf16x8 qf1 = *(const bf16x8*)(Qp + 32);

  const bf16* Bg = biasb + (size_t)qg0*2048;       // rows qg0..qg0+3

  f32x4 O[4];
  float l[4] = {0.f,0.f,0.f,0.f};
  #pragma unroll
  for (int c=0;c<4;++c)
    #pragma unroll
    for (int r=0;r<4;++r) O[c][r] = 0.f;

  int rK0[4], rK1[4];
  #pragma unroll
  for (int c=0;c<4;++c){
    const int row = c*16 + l16;
    rK0[c] = row*64 + (((lg  ) ^ (row&7))<<3);
    rK1[c] = row*64 + (((4+lg) ^ (row&7))<<3);
  }

  // bias for current tile, prefetched one iteration ahead (w_h folded in)
  float bc[4][4];
  #pragma unroll
  for (int c=0;c<4;++c)
    #pragma unroll
    for (int r=0;r<4;++r)
      bc[c][r] = w_h * (float)Bg[(size_t)r*2048 + c*16 + l16];

  // prologue: stage tile 0
  {
    bf16x8 k0v = *(const bf16x8*)Kg;
    bf16x8 v0v = *(const bf16x8*)Vg;
    *(bf16x8*)&Kl[0][wsw] = k0v;
    *(bf16x8*)&Vl[0][wsw] = v0v;
  }
  __syncthreads();

  int cur = 0;
  for (int kt=0; kt<nkt; ++kt){
    const int k0 = kt*64;
    const bool more = (kt+1 < nkt);
    bf16x8 kA, vA;
    float bn[4][4];
    if (more){
      kA = *(const bf16x8*)(Kg + (size_t)(k0+64)*64);
      vA = *(const bf16x8*)(Vg + (k0+64));
      #pragma unroll
      for (int c=0;c<4;++c)
        #pragma unroll
        for (int r=0;r<4;++r)
          bn[c][r] = w_h * (float)Bg[(size_t)r*2048 + (k0+64) + c*16 + l16];
    }

    if (k0 <= qbase + 15){                 // wave-uniform skip of fully-masked tiles
      f32x4 S[4];
      #pragma unroll
      for (int c=0;c<4;++c)
        #pragma unroll
        for (int r=0;r<4;++r) S[c][r] = bc[c][r];

      __builtin_amdgcn_s_setprio(1);
      #pragma unroll
      for (int c=0;c<4;++c){
        bf16x8 kf0 = *(const bf16x8*)&Kl[cur][rK0[c]];
        bf16x8 kf1 = *(const bf16x8*)&Kl[cur][rK1[c]];
        S[c] = MFMA_BF16(qf0, kf0, S[c]);
        S[c] = MFMA_BF16(qf1, kf1, S[c]);
      }
      __builtin_amdgcn_s_setprio(0);

      #pragma unroll
      for (int c=0;c<4;++c){
        const int kg = k0 + c*16 + l16;
        #pragma unroll
        for (int r=0;r<4;++r){
          float s = S[c][r];
          if (kg > qg0+r) s = -1e30f;
          const float p = __expf(s - 4.0f);
          S[c][r] = p; l[r] += p;
        }
      }

      #pragma unroll
      for (int c=0;c<4;++c)
        #pragma unroll
        for (int r=0;r<4;++r)
          plds[wid][lg*4+r][c*16+l16] = (bf16)S[c][r];
      bf16x8 pf0 = *(const bf16x8*)&plds[wid][l16][lg*8];
      bf16x8 pf1 = *(const bf16x8*)&plds[wid][l16][lg*8+32];

      __builtin_amdgcn_s_setprio(1);
      #pragma unroll
      for (int c=0;c<4;++c){
        bf16x8 vf0 = *(const bf16x8*)&Vl[cur][rK0[c]];
        bf16x8 vf1 = *(const bf16x8*)&Vl[cur][rK1[c]];
        O[c] = MFMA_BF16(pf0, vf0, O[c]);
        O[c] = MFMA_BF16(pf1, vf1, O[c]);
      }
      __builtin_amdgcn_s_setprio(0);
    }

    if (more){
      *(bf16x8*)&Kl[cur^1][wsw] = kA;
      *(bf16x8*)&Vl[cur^1][wsw] = vA;
      #pragma unroll
      for (int c=0;c<4;++c)
        #pragma unroll
        for (int r=0;r<4;++r) bc[c][r] = bn[c][r];
    }
    __syncthreads();
    cur ^= (int)more;
  }

  #pragma unroll
  for (int r=0;r<4;++r){
    float v = l[r];
    v += __shfl_xor(v,1);
    v += __shfl_xor(v,2);
    v += __shfl_xor(v,4);
    v += __shfl_xor(v,8);
    l[r] = 1.0f / v;
  }
  #pragma unroll
  for (int c=0;c<4;++c)
    #pragma unroll
    for (int r=0;r<4;++r)
      attout[(size_t)(qg0+r)*2048 + h*64 + c*16 + l16] = (bf16)(O[c][r]*l[r]);
}

// ---------------- launcher ----------------
extern "C" void kernel_launch(void* const* d_in, const int* in_sizes, int n_in,
                              void* d_out, int out_size, void* d_ws, size_t ws_size,
                              hipStream_t stream){
  const float* x    = (const float*)d_in[0];
  const float* bias = (const float*)d_in[2];
  const float* mw   = (const float*)d_in[3];
  const float* Wq   = (const float*)d_in[4];
  const float* Wk   = (const float*)d_in[5];
  const float* Wv   = (const float*)d_in[6];
  const float* Wo   = (const float*)d_in[7];
  const float* ts   = (const float*)d_in[8];
  float* out = (float*)d_out;

  const size_t SZ = (size_t)2048*2048;
  bf16* base = (bf16*)d_ws;
  bf16* xb   = base;
  bf16* Wqb  = base + 1*SZ;
  bf16* Wkb  = base + 2*SZ;
  bf16* Wvb  = base + 3*SZ;
  bf16* Wob  = base + 4*SZ;
  bf16* bb   = base + 5*SZ;
  bf16* Qsb  = base + 6*SZ;
  bf16* Ksb  = base + 7*SZ;
  bf16* Vtb  = base + 8*SZ;
  bf16* att  = base + 9*SZ;
  float* cosT = (float*)(base + 10*SZ);
  float* sinT = cosT + 2048*32;

  CvtArgs ca;
  ca.src[0]=x;  ca.src[1]=Wq;  ca.src[2]=Wk;  ca.src[3]=Wv;  ca.src[4]=Wo;  ca.src[5]=bias;
  ca.dst[0]=xb; ca.dst[1]=Wqb; ca.dst[2]=Wkb; ca.dst[3]=Wvb; ca.dst[4]=Wob; ca.dst[5]=bb;
  const int nb = (int)(SZ/8/256);
  cvt6_kernel<<<dim3(nb,6),256,0,stream>>>(ca, (int)SZ);
  rope_tab_kernel<<<256,256,0,stream>>>(cosT, sinT);
  gemm_qkv256_kernel<<<dim3(8,8,3),512,0,stream>>>(xb, Wqb,Wkb,Wvb,
                                                   Qsb,Ksb,Vtb, cosT,sinT, mw,ts);
  attn_kernel<<<512,512,0,stream>>>(Qsb,Ksb,Vtb,bb,mw,att);
  gemm_out_kernel<<<dim3(16,16),256,0,stream>>>(att, Wob, out);
}

// Round 14
// 168.970 us; speedup vs baseline: 1.1599x; 1.0772x over previous
//
#include <hip/hip_runtime.h>
#include <hip/hip_bf16.h>
#include <cstdint>
#include <cstddef>

typedef __bf16 bf16;
typedef bf16 bf16x4 __attribute__((ext_vector_type(4)));
typedef bf16 bf16x8 __attribute__((ext_vector_type(8)));
typedef float f32x4 __attribute__((ext_vector_type(4)));

#define MFMA_BF16(a,b,c) __builtin_amdgcn_mfma_f32_16x16x32_bf16((a),(b),(c),0,0,0)

typedef __attribute__((address_space(1))) const void gvoid;
typedef __attribute__((address_space(3))) void svoid;
__device__ __forceinline__ void gload16(const bf16* g, bf16* l){
  __builtin_amdgcn_global_load_lds((gvoid*)g, (svoid*)l, 16, 0, 0);
}

// HEAD_COUNTS = [8,6,4,4,6,4] -> boundaries 8,14,18,22,28,32
__device__ __forceinline__ int head_group(int h){
  return (h<8)?0:(h<14)?1:(h<18)?2:(h<22)?3:(h<28)?4:5;
}

// ---------------- fused f32->bf16 convert (6 tensors) + RoPE tables in one launch ----------
struct CvtArgs { const float* src[6]; bf16* dst[6]; };
__global__ __launch_bounds__(256) void cvt_rope_kernel(CvtArgs a, int n,
                                                       float* __restrict__ cosT,
                                                       float* __restrict__ sinT){
  const int z = blockIdx.y;
  if (z == 6){                              // RoPE cos/sin tables: [T][32] f32
    if (blockIdx.x >= 256) return;
    const int t = blockIdx.x*8 + (threadIdx.x>>5);
    const int i = threadIdx.x&31;
    float invf = powf(10000.0f, -((float)i)/32.0f);
    float ang = (float)t * invf;
    cosT[t*32+i] = cosf(ang);
    sinT[t*32+i] = sinf(ang);
    return;
  }
  const float* __restrict__ in = a.src[z];
  bf16* __restrict__ out = a.dst[z];
  int i = (blockIdx.x*256 + threadIdx.x)*8;
  if (i >= n) return;
  const float4* p = (const float4*)(in + i);
  float4 va = p[0], vb = p[1];
  bf16x8 o;
  o[0]=(bf16)va.x; o[1]=(bf16)va.y; o[2]=(bf16)va.z; o[3]=(bf16)va.w;
  o[4]=(bf16)vb.x; o[5]=(bf16)vb.y; o[6]=(bf16)vb.z; o[7]=(bf16)vb.w;
  *(bf16x8*)(out+i) = o;
}

// ---------------- GEMM core: acc = A[M,K] * B[N,K]^T, 128x128 tile ----------------
// m97 structure: BK=32, linear LDS, global_load_lds width=16, 2 barriers/K-step.
__device__ __forceinline__ void gemm_core(const bf16* __restrict__ A,
                                          const bf16* __restrict__ B,
                                          int row0, int col0,
                                          f32x4 (&acc)[4][4]){
  __shared__ bf16 As[128*32];
  __shared__ bf16 Bs[128*32];
  const int tid  = threadIdx.x;
  const int wave = tid>>6, lane = tid&63;
  const int l16  = lane&15, lg = lane>>4;
  const int wr   = wave>>1, wc = wave&1;

  const bf16* Ag0 = A + (size_t)(row0 + wave*32      + (lane>>2))*2048 + (lane&3)*8;
  const bf16* Ag1 = A + (size_t)(row0 + wave*32 + 16 + (lane>>2))*2048 + (lane&3)*8;
  const bf16* Bg0 = B + (size_t)(col0 + wave*32      + (lane>>2))*2048 + (lane&3)*8;
  const bf16* Bg1 = B + (size_t)(col0 + wave*32 + 16 + (lane>>2))*2048 + (lane&3)*8;
  bf16* AsB0 = As + (wave*32     )*32;
  bf16* AsB1 = As + (wave*32 + 16)*32;
  bf16* BsB0 = Bs + (wave*32     )*32;
  bf16* BsB1 = Bs + (wave*32 + 16)*32;

  #pragma unroll
  for (int m=0;m<4;++m)
    #pragma unroll
    for (int n=0;n<4;++n)
      #pragma unroll
      for (int r=0;r<4;++r) acc[m][n][r] = 0.f;

  for (int kt=0; kt<64; ++kt){
    const int ko = kt*32;
    gload16(Ag0 + ko, AsB0);
    gload16(Ag1 + ko, AsB1);
    gload16(Bg0 + ko, BsB0);
    gload16(Bg1 + ko, BsB1);
    __syncthreads();
    bf16x8 af[4], bfr[4];
    #pragma unroll
    for (int m=0;m<4;++m) af[m]  = *(const bf16x8*)&As[(wr*64+m*16+l16)*32 + lg*8];
    #pragma unroll
    for (int n=0;n<4;++n) bfr[n] = *(const bf16x8*)&Bs[(wc*64+n*16+l16)*32 + lg*8];
    #pragma unroll
    for (int m=0;m<4;++m)
      #pragma unroll
      for (int n=0;n<4;++n)
        acc[m][n] = MFMA_BF16(af[m], bfr[n], acc[m][n]);
    __syncthreads();
  }
}

// ---------------- QKV GEMM with fused RoPE / relayout / V-transpose epilogues ----------------
__global__ __launch_bounds__(256) void gemm_qkv_kernel(
    const bf16* __restrict__ A,
    const bf16* __restrict__ B0, const bf16* __restrict__ B1, const bf16* __restrict__ B2,
    bf16* __restrict__ Qs, bf16* __restrict__ Ks, bf16* __restrict__ Vt,
    const float* __restrict__ cosT, const float* __restrict__ sinT,
    const float* __restrict__ mw, const float* __restrict__ ts){
  const int z = blockIdx.z;
  const bf16* B = (z==0)?B0:((z==1)?B1:B2);
  const int row0 = blockIdx.y*128, col0 = blockIdx.x*128;

  f32x4 acc[4][4];
  gemm_core(A, B, row0, col0, acc);

  const int tid  = threadIdx.x;
  const int wave = tid>>6, lane = tid&63;
  const int l16  = lane&15, lg = lane>>4;
  const int wr   = wave>>1, wc = wave&1;
  const int h    = (col0 + wc*64) >> 6;      // wave's 64-col span = one head

  if (z == 2){
    // V-transpose epilogue: acc[m][n][0..3] = 4 consecutive t -> one 8B store
    #pragma unroll
    for (int n=0;n<4;++n){
      const int d = n*16 + l16;
      #pragma unroll
      for (int m=0;m<4;++m){
        const int t0 = row0 + wr*64 + m*16 + lg*4;
        bf16x4 v;
        #pragma unroll
        for (int r=0;r<4;++r) v[r] = (bf16)acc[m][n][r];
        *(bf16x4*)&Vt[((size_t)h*64 + d)*2048 + t0] = v;
      }
    }
  } else {
    const float sc = (z==0) ? 0.125f*ts[h]*mw[head_group(h)] : 1.0f;
    bf16* Out = (z==0) ? Qs : Ks;
    #pragma unroll
    for (int m=0;m<4;++m){
      #pragma unroll
      for (int r=0;r<4;++r){
        const int t = row0 + wr*64 + m*16 + lg*4 + r;
        const float* ct = cosT + t*32;
        const float* st = sinT + t*32;
        bf16* dst = Out + ((size_t)h*2048 + t)*64;
        #pragma unroll
        for (int n=0;n<2;++n){
          const int i = n*16 + l16;
          const float c = ct[i], s = st[i];
          const float a1 = acc[m][n][r], a2 = acc[m][n+2][r];
          dst[i]    = (bf16)((a1*c - a2*s)*sc);
          dst[i+32] = (bf16)((a2*c + a1*s)*sc);
        }
      }
    }
  }
}

// ---------------- output GEMM: 128x64 tile (512 blocks -> 2 blocks/CU) ----------------
// Same m97 staging/fragment pattern; B-tile is 64 rows, staged 1 gload16/thread
// (wave w covers rows w*16..w*16+15; LDS lin offset = wave*512 + lane*8 elems).
__global__ __launch_bounds__(256) void gemm_out_kernel(
    const bf16* __restrict__ A, const bf16* __restrict__ B, float* __restrict__ C){
  __shared__ bf16 As[128*32];
  __shared__ bf16 Bs[64*32];
  const int row0 = blockIdx.y*128, col0 = blockIdx.x*64;
  const int tid  = threadIdx.x;
  const int wave = tid>>6, lane = tid&63;
  const int l16  = lane&15, lg = lane>>4;
  const int wr   = wave>>1, wc = wave&1;

  const bf16* Ag0 = A + (size_t)(row0 + wave*32      + (lane>>2))*2048 + (lane&3)*8;
  const bf16* Ag1 = A + (size_t)(row0 + wave*32 + 16 + (lane>>2))*2048 + (lane&3)*8;
  const bf16* Bg0 = B + (size_t)(col0 + wave*16      + (lane>>2))*2048 + (lane&3)*8;
  bf16* AsB0 = As + (wave*32     )*32;
  bf16* AsB1 = As + (wave*32 + 16)*32;
  bf16* BsB0 = Bs + (wave*16     )*32;

  f32x4 acc[4][2];
  #pragma unroll
  for (int m=0;m<4;++m)
    #pragma unroll
    for (int n=0;n<2;++n)
      #pragma unroll
      for (int r=0;r<4;++r) acc[m][n][r] = 0.f;

  for (int kt=0; kt<64; ++kt){
    const int ko = kt*32;
    gload16(Ag0 + ko, AsB0);
    gload16(Ag1 + ko, AsB1);
    gload16(Bg0 + ko, BsB0);
    __syncthreads();
    bf16x8 af[4], bfr[2];
    #pragma unroll
    for (int m=0;m<4;++m) af[m]  = *(const bf16x8*)&As[(wr*64+m*16+l16)*32 + lg*8];
    #pragma unroll
    for (int n=0;n<2;++n) bfr[n] = *(const bf16x8*)&Bs[(wc*32+n*16+l16)*32 + lg*8];
    #pragma unroll
    for (int m=0;m<4;++m)
      #pragma unroll
      for (int n=0;n<2;++n)
        acc[m][n] = MFMA_BF16(af[m], bfr[n], acc[m][n]);
    __syncthreads();
  }

  #pragma unroll
  for (int m=0;m<4;++m)
    #pragma unroll
    for (int n=0;n<2;++n)
      #pragma unroll
      for (int r=0;r<4;++r){
        size_t idx = (size_t)(row0 + wr*64 + m*16 + lg*4 + r)*2048
                   + col0 + wc*32 + n*16 + l16;
        C[idx] = acc[m][n][r];
      }
}

// ---------------- fused causal attention (r8 verbatim: best measured, ~60us) ----------
__global__ __launch_bounds__(512) void attn_kernel(
    const bf16* __restrict__ Qs, const bf16* __restrict__ Ks,
    const bf16* __restrict__ Vt, const bf16* __restrict__ biasb,
    const float* __restrict__ mw, bf16* __restrict__ attout){
  const int n  = blockIdx.x;                       // 0..511
  const int h  = ((n>>8)<<4) | ((n>>4)&15);        // 0..31
  const int qt = (n&256) ? (n&15) : 15-(n&15);     // paired: qt(n)+qt(n+256)=15
  const int tid = threadIdx.x, wid = tid>>6, lane = tid&63;
  const int l16 = lane&15, lg = lane>>4;
  const float w_h = mw[head_group(h)];
  const int qbase = qt*128 + wid*16;
  const int qg0 = qbase + lg*4;                    // +r = this lane's q rows
  const int nkt = 2*qt + 2;

  __shared__ bf16 Kl[2][4096];
  __shared__ bf16 Vl[2][4096];
  __shared__ bf16 plds[8][16][72];

  // staging: 512 threads, one b128 per tensor per tile
  const int srow = tid>>3, ssub = tid&7;
  const bf16* Kg = Ks + (size_t)h*2048*64 + srow*64 + ssub*8;   // + k0*64
  const bf16* Vg = Vt + ((size_t)h*64 + srow)*2048 + ssub*8;    // + k0
  const int wsw = srow*64 + ((ssub ^ (srow&7))<<3);

  // Q fragments (registers, whole kernel)
  const bf16* Qp = Qs + ((size_t)h*2048 + qbase + l16)*64 + lg*8;
  bf16x8 qf0 = *(const bf16x8*)Qp;
  bf16x8 qf1 = *(const bf16x8*)(Qp + 32);

  const bf16* Bg = biasb + (size_t)qg0*2048;       // rows qg0..qg0+3

  f32x4 O[4];
  float l[4] = {0.f,0.f,0.f,0.f};
  #pragma unroll
  for (int c=0;c<4;++c)
    #pragma unroll
    for (int r=0;r<4;++r) O[c][r] = 0.f;

  int rK0[4], rK1[4];
  #pragma unroll
  for (int c=0;c<4;++c){
    const int row = c*16 + l16;
    rK0[c] = row*64 + (((lg  ) ^ (row&7))<<3);
    rK1[c] = row*64 + (((4+lg) ^ (row&7))<<3);
  }

  // bias for current tile, prefetched one iteration ahead (w_h folded in)
  float bc[4][4];
  #pragma unroll
  for (int c=0;c<4;++c)
    #pragma unroll
    for (int r=0;r<4;++r)
      bc[c][r] = w_h * (float)Bg[(size_t)r*2048 + c*16 + l16];

  // prologue: stage tile 0
  {
    bf16x8 k0v = *(const bf16x8*)Kg;
    bf16x8 v0v = *(const bf16x8*)Vg;
    *(bf16x8*)&Kl[0][wsw] = k0v;
    *(bf16x8*)&Vl[0][wsw] = v0v;
  }
  __syncthreads();

  int cur = 0;
  for (int kt=0; kt<nkt; ++kt){
    const int k0 = kt*64;
    const bool more = (kt+1 < nkt);
    bf16x8 kA, vA;
    float bn[4][4];
    if (more){
      kA = *(const bf16x8*)(Kg + (size_t)(k0+64)*64);
      vA = *(const bf16x8*)(Vg + (k0+64));
      #pragma unroll
      for (int c=0;c<4;++c)
        #pragma unroll
        for (int r=0;r<4;++r)
          bn[c][r] = w_h * (float)Bg[(size_t)r*2048 + (k0+64) + c*16 + l16];
    }

    if (k0 <= qbase + 15){                 // wave-uniform skip of fully-masked tiles
      f32x4 S[4];
      #pragma unroll
      for (int c=0;c<4;++c)
        #pragma unroll
        for (int r=0;r<4;++r) S[c][r] = bc[c][r];

      __builtin_amdgcn_s_setprio(1);
      #pragma unroll
      for (int c=0;c<4;++c){
        bf16x8 kf0 = *(const bf16x8*)&Kl[cur][rK0[c]];
        bf16x8 kf1 = *(const bf16x8*)&Kl[cur][rK1[c]];
        S[c] = MFMA_BF16(qf0, kf0, S[c]);
        S[c] = MFMA_BF16(qf1, kf1, S[c]);
      }
      __builtin_amdgcn_s_setprio(0);

      #pragma unroll
      for (int c=0;c<4;++c){
        const int kg = k0 + c*16 + l16;
        #pragma unroll
        for (int r=0;r<4;++r){
          float s = S[c][r];
          if (kg > qg0+r) s = -1e30f;
          const float p = __expf(s - 4.0f);
          S[c][r] = p; l[r] += p;
        }
      }

      #pragma unroll
      for (int c=0;c<4;++c)
        #pragma unroll
        for (int r=0;r<4;++r)
          plds[wid][lg*4+r][c*16+l16] = (bf16)S[c][r];
      bf16x8 pf0 = *(const bf16x8*)&plds[wid][l16][lg*8];
      bf16x8 pf1 = *(const bf16x8*)&plds[wid][l16][lg*8+32];

      __builtin_amdgcn_s_setprio(1);
      #pragma unroll
      for (int c=0;c<4;++c){
        bf16x8 vf0 = *(const bf16x8*)&Vl[cur][rK0[c]];
        bf16x8 vf1 = *(const bf16x8*)&Vl[cur][rK1[c]];
        O[c] = MFMA_BF16(pf0, vf0, O[c]);
        O[c] = MFMA_BF16(pf1, vf1, O[c]);
      }
      __builtin_amdgcn_s_setprio(0);
    }

    if (more){
      *(bf16x8*)&Kl[cur^1][wsw] = kA;
      *(bf16x8*)&Vl[cur^1][wsw] = vA;
      #pragma unroll
      for (int c=0;c<4;++c)
        #pragma unroll
        for (int r=0;r<4;++r) bc[c][r] = bn[c][r];
    }
    __syncthreads();
    cur ^= (int)more;
  }

  #pragma unroll
  for (int r=0;r<4;++r){
    float v = l[r];
    v += __shfl_xor(v,1);
    v += __shfl_xor(v,2);
    v += __shfl_xor(v,4);
    v += __shfl_xor(v,8);
    l[r] = 1.0f / v;
  }
  #pragma unroll
  for (int c=0;c<4;++c)
    #pragma unroll
    for (int r=0;r<4;++r)
      attout[(size_t)(qg0+r)*2048 + h*64 + c*16 + l16] = (bf16)(O[c][r]*l[r]);
}

// ---------------- launcher ----------------
extern "C" void kernel_launch(void* const* d_in, const int* in_sizes, int n_in,
                              void* d_out, int out_size, void* d_ws, size_t ws_size,
                              hipStream_t stream){
  const float* x    = (const float*)d_in[0];
  const float* bias = (const float*)d_in[2];
  const float* mw   = (const float*)d_in[3];
  const float* Wq   = (const float*)d_in[4];
  const float* Wk   = (const float*)d_in[5];
  const float* Wv   = (const float*)d_in[6];
  const float* Wo   = (const float*)d_in[7];
  const float* ts   = (const float*)d_in[8];
  float* out = (float*)d_out;

  const size_t SZ = (size_t)2048*2048;
  bf16* base = (bf16*)d_ws;
  bf16* xb   = base;
  bf16* Wqb  = base + 1*SZ;
  bf16* Wkb  = base + 2*SZ;
  bf16* Wvb  = base + 3*SZ;
  bf16* Wob  = base + 4*SZ;
  bf16* bb   = base + 5*SZ;
  bf16* Qsb  = base + 6*SZ;
  bf16* Ksb  = base + 7*SZ;
  bf16* Vtb  = base + 8*SZ;
  bf16* att  = base + 9*SZ;
  float* cosT = (float*)(base + 10*SZ);
  float* sinT = cosT + 2048*32;

  CvtArgs ca;
  ca.src[0]=x;  ca.src[1]=Wq;  ca.src[2]=Wk;  ca.src[3]=Wv;  ca.src[4]=Wo;  ca.src[5]=bias;
  ca.dst[0]=xb; ca.dst[1]=Wqb; ca.dst[2]=Wkb; ca.dst[3]=Wvb; ca.dst[4]=Wob; ca.dst[5]=bb;
  const int nb = (int)(SZ/8/256);
  cvt_rope_kernel<<<dim3(nb,7),256,0,stream>>>(ca, (int)SZ, cosT, sinT);
  gemm_qkv_kernel<<<dim3(16,16,3),256,0,stream>>>(xb, Wqb,Wkb,Wvb,
                                                  Qsb,Ksb,Vtb, cosT,sinT, mw,ts);
  attn_kernel<<<512,512,0,stream>>>(Qsb,Ksb,Vtb,bb,mw,att);
  gemm_out_kernel<<<dim3(32,16),256,0,stream>>>(att, Wob, out);
}

// Round 15
// 165.218 us; speedup vs baseline: 1.1863x; 1.0227x over previous
//
#include <hip/hip_runtime.h>
#include <hip/hip_bf16.h>
#include <cstdint>
#include <cstddef>

typedef __bf16 bf16;
typedef bf16 bf16x4 __attribute__((ext_vector_type(4)));
typedef bf16 bf16x8 __attribute__((ext_vector_type(8)));
typedef float f32x4 __attribute__((ext_vector_type(4)));

#define MFMA_BF16(a,b,c) __builtin_amdgcn_mfma_f32_16x16x32_bf16((a),(b),(c),0,0,0)

typedef __attribute__((address_space(1))) const void gvoid;
typedef __attribute__((address_space(3))) void svoid;
__device__ __forceinline__ void gload16(const bf16* g, bf16* l){
  __builtin_amdgcn_global_load_lds((gvoid*)g, (svoid*)l, 16, 0, 0);
}

// HEAD_COUNTS = [8,6,4,4,6,4] -> boundaries 8,14,18,22,28,32
__device__ __forceinline__ int head_group(int h){
  return (h<8)?0:(h<14)?1:(h<18)?2:(h<22)?3:(h<28)?4:5;
}

// ---------------- fused f32->bf16 convert (5 tensors) + RoPE tables in one launch ----------
struct CvtArgs { const float* src[5]; bf16* dst[5]; };
__global__ __launch_bounds__(256) void cvt_rope_kernel(CvtArgs a, int n,
                                                       float* __restrict__ cosT,
                                                       float* __restrict__ sinT){
  const int z = blockIdx.y;
  if (z == 5){                              // RoPE cos/sin tables: [T][32] f32
    if (blockIdx.x >= 256) return;
    const int t = blockIdx.x*8 + (threadIdx.x>>5);
    const int i = threadIdx.x&31;
    float invf = powf(10000.0f, -((float)i)/32.0f);
    float ang = (float)t * invf;
    cosT[t*32+i] = cosf(ang);
    sinT[t*32+i] = sinf(ang);
    return;
  }
  const float* __restrict__ in = a.src[z];
  bf16* __restrict__ out = a.dst[z];
  int i = (blockIdx.x*256 + threadIdx.x)*8;
  if (i >= n) return;
  const float4* p = (const float4*)(in + i);
  float4 va = p[0], vb = p[1];
  bf16x8 o;
  o[0]=(bf16)va.x; o[1]=(bf16)va.y; o[2]=(bf16)va.z; o[3]=(bf16)va.w;
  o[4]=(bf16)vb.x; o[5]=(bf16)vb.y; o[6]=(bf16)vb.z; o[7]=(bf16)vb.w;
  *(bf16x8*)(out+i) = o;
}

// ---------------- GEMM core: acc = A[M,K] * B[N,K]^T, 128x128 tile ----------------
// m97 structure: BK=32, linear LDS, global_load_lds width=16, 2 barriers/K-step.
__device__ __forceinline__ void gemm_core(const bf16* __restrict__ A,
                                          const bf16* __restrict__ B,
                                          int row0, int col0,
                                          f32x4 (&acc)[4][4]){
  __shared__ bf16 As[128*32];
  __shared__ bf16 Bs[128*32];
  const int tid  = threadIdx.x;
  const int wave = tid>>6, lane = tid&63;
  const int l16  = lane&15, lg = lane>>4;
  const int wr   = wave>>1, wc = wave&1;

  const bf16* Ag0 = A + (size_t)(row0 + wave*32      + (lane>>2))*2048 + (lane&3)*8;
  const bf16* Ag1 = A + (size_t)(row0 + wave*32 + 16 + (lane>>2))*2048 + (lane&3)*8;
  const bf16* Bg0 = B + (size_t)(col0 + wave*32      + (lane>>2))*2048 + (lane&3)*8;
  const bf16* Bg1 = B + (size_t)(col0 + wave*32 + 16 + (lane>>2))*2048 + (lane&3)*8;
  bf16* AsB0 = As + (wave*32     )*32;
  bf16* AsB1 = As + (wave*32 + 16)*32;
  bf16* BsB0 = Bs + (wave*32     )*32;
  bf16* BsB1 = Bs + (wave*32 + 16)*32;

  #pragma unroll
  for (int m=0;m<4;++m)
    #pragma unroll
    for (int n=0;n<4;++n)
      #pragma unroll
      for (int r=0;r<4;++r) acc[m][n][r] = 0.f;

  for (int kt=0; kt<64; ++kt){
    const int ko = kt*32;
    gload16(Ag0 + ko, AsB0);
    gload16(Ag1 + ko, AsB1);
    gload16(Bg0 + ko, BsB0);
    gload16(Bg1 + ko, BsB1);
    __syncthreads();
    bf16x8 af[4], bfr[4];
    #pragma unroll
    for (int m=0;m<4;++m) af[m]  = *(const bf16x8*)&As[(wr*64+m*16+l16)*32 + lg*8];
    #pragma unroll
    for (int n=0;n<4;++n) bfr[n] = *(const bf16x8*)&Bs[(wc*64+n*16+l16)*32 + lg*8];
    #pragma unroll
    for (int m=0;m<4;++m)
      #pragma unroll
      for (int n=0;n<4;++n)
        acc[m][n] = MFMA_BF16(af[m], bfr[n], acc[m][n]);
    __syncthreads();
  }
}

// ---------------- QKV GEMM with fused RoPE / relayout / V-transpose epilogues ----------------
__global__ __launch_bounds__(256) void gemm_qkv_kernel(
    const bf16* __restrict__ A,
    const bf16* __restrict__ B0, const bf16* __restrict__ B1, const bf16* __restrict__ B2,
    bf16* __restrict__ Qs, bf16* __restrict__ Ks, bf16* __restrict__ Vt,
    const float* __restrict__ cosT, const float* __restrict__ sinT,
    const float* __restrict__ mw, const float* __restrict__ ts){
  const int z = blockIdx.z;
  const bf16* B = (z==0)?B0:((z==1)?B1:B2);
  const int row0 = blockIdx.y*128, col0 = blockIdx.x*128;

  f32x4 acc[4][4];
  gemm_core(A, B, row0, col0, acc);

  const int tid  = threadIdx.x;
  const int wave = tid>>6, lane = tid&63;
  const int l16  = lane&15, lg = lane>>4;
  const int wr   = wave>>1, wc = wave&1;
  const int h    = (col0 + wc*64) >> 6;      // wave's 64-col span = one head

  if (z == 2){
    // V-transpose epilogue: acc[m][n][0..3] = 4 consecutive t -> one 8B store
    #pragma unroll
    for (int n=0;n<4;++n){
      const int d = n*16 + l16;
      #pragma unroll
      for (int m=0;m<4;++m){
        const int t0 = row0 + wr*64 + m*16 + lg*4;
        bf16x4 v;
        #pragma unroll
        for (int r=0;r<4;++r) v[r] = (bf16)acc[m][n][r];
        *(bf16x4*)&Vt[((size_t)h*64 + d)*2048 + t0] = v;
      }
    }
  } else {
    const float sc = (z==0) ? 0.125f*ts[h]*mw[head_group(h)] : 1.0f;
    bf16* Out = (z==0) ? Qs : Ks;
    #pragma unroll
    for (int m=0;m<4;++m){
      #pragma unroll
      for (int r=0;r<4;++r){
        const int t = row0 + wr*64 + m*16 + lg*4 + r;
        const float* ct = cosT + t*32;
        const float* st = sinT + t*32;
        bf16* dst = Out + ((size_t)h*2048 + t)*64;
        #pragma unroll
        for (int n=0;n<2;++n){
          const int i = n*16 + l16;
          const float c = ct[i], s = st[i];
          const float a1 = acc[m][n][r], a2 = acc[m][n+2][r];
          dst[i]    = (bf16)((a1*c - a2*s)*sc);
          dst[i+32] = (bf16)((a2*c + a1*s)*sc);
        }
      }
    }
  }
}

// ---------------- output GEMM: 128x64 tile (512 blocks -> 2 blocks/CU) ----------------
__global__ __launch_bounds__(256) void gemm_out_kernel(
    const bf16* __restrict__ A, const bf16* __restrict__ B, float* __restrict__ C){
  __shared__ bf16 As[128*32];
  __shared__ bf16 Bs[64*32];
  const int row0 = blockIdx.y*128, col0 = blockIdx.x*64;
  const int tid  = threadIdx.x;
  const int wave = tid>>6, lane = tid&63;
  const int l16  = lane&15, lg = lane>>4;
  const int wr   = wave>>1, wc = wave&1;

  const bf16* Ag0 = A + (size_t)(row0 + wave*32      + (lane>>2))*2048 + (lane&3)*8;
  const bf16* Ag1 = A + (size_t)(row0 + wave*32 + 16 + (lane>>2))*2048 + (lane&3)*8;
  const bf16* Bg0 = B + (size_t)(col0 + wave*16      + (lane>>2))*2048 + (lane&3)*8;
  bf16* AsB0 = As + (wave*32     )*32;
  bf16* AsB1 = As + (wave*32 + 16)*32;
  bf16* BsB0 = Bs + (wave*16     )*32;

  f32x4 acc[4][2];
  #pragma unroll
  for (int m=0;m<4;++m)
    #pragma unroll
    for (int n=0;n<2;++n)
      #pragma unroll
      for (int r=0;r<4;++r) acc[m][n][r] = 0.f;

  for (int kt=0; kt<64; ++kt){
    const int ko = kt*32;
    gload16(Ag0 + ko, AsB0);
    gload16(Ag1 + ko, AsB1);
    gload16(Bg0 + ko, BsB0);
    __syncthreads();
    bf16x8 af[4], bfr[2];
    #pragma unroll
    for (int m=0;m<4;++m) af[m]  = *(const bf16x8*)&As[(wr*64+m*16+l16)*32 + lg*8];
    #pragma unroll
    for (int n=0;n<2;++n) bfr[n] = *(const bf16x8*)&Bs[(wc*32+n*16+l16)*32 + lg*8];
    #pragma unroll
    for (int m=0;m<4;++m)
      #pragma unroll
      for (int n=0;n<2;++n)
        acc[m][n] = MFMA_BF16(af[m], bfr[n], acc[m][n]);
    __syncthreads();
  }

  #pragma unroll
  for (int m=0;m<4;++m)
    #pragma unroll
    for (int n=0;n<2;++n)
      #pragma unroll
      for (int r=0;r<4;++r){
        size_t idx = (size_t)(row0 + wr*64 + m*16 + lg*4 + r)*2048
                   + col0 + wc*32 + n*16 + l16;
        C[idx] = acc[m][n][r];
      }
}

// ---------------- fused causal attention ----------------
// r8 inner loop verbatim. Changes this round:
//  * bias read f32 DIRECT from the input (cvt slice removed), same 1-iter prefetch.
//  * XCD-grouped heads: h = ((n&7)<<2)|((n>>3)&3) -> XCD (n&7) serves heads 4x..4x+3
//    (2MB K/V per 4MB private L2). Complementary pairing kept: qt(n)+qt(n+256)=15,
//    long blocks dispatched first, per-CU total = 34 iters.
__global__ __launch_bounds__(512) void attn_kernel(
    const bf16* __restrict__ Qs, const bf16* __restrict__ Ks,
    const bf16* __restrict__ Vt, const float* __restrict__ biasf,
    const float* __restrict__ mw, bf16* __restrict__ attout){
  const int n  = blockIdx.x;                       // 0..511
  const int h  = ((n&7)<<2) | ((n>>3)&3);          // 0..31, XCD-grouped
  const int qt = (n&256) ? ((n>>5)&7) : 15-((n>>5)&7);
  const int tid = threadIdx.x, wid = tid>>6, lane = tid&63;
  const int l16 = lane&15, lg = lane>>4;
  const float w_h = mw[head_group(h)];
  const int qbase = qt*128 + wid*16;
  const int qg0 = qbase + lg*4;                    // +r = this lane's q rows
  const int nkt = 2*qt + 2;

  __shared__ bf16 Kl[2][4096];
  __shared__ bf16 Vl[2][4096];
  __shared__ bf16 plds[8][16][72];

  // staging: 512 threads, one b128 per tensor per tile
  const int srow = tid>>3, ssub = tid&7;
  const bf16* Kg = Ks + (size_t)h*2048*64 + srow*64 + ssub*8;   // + k0*64
  const bf16* Vg = Vt + ((size_t)h*64 + srow)*2048 + ssub*8;    // + k0
  const int wsw = srow*64 + ((ssub ^ (srow&7))<<3);

  // Q fragments (registers, whole kernel)
  const bf16* Qp = Qs + ((size_t)h*2048 + qbase + l16)*64 + lg*8;
  bf16x8 qf0 = *(const bf16x8*)Qp;
  bf16x8 qf1 = *(const bf16x8*)(Qp + 32);

  const float* Bg = biasf + (size_t)qg0*2048;      // rows qg0..qg0+3

  f32x4 O[4];
  float l[4] = {0.f,0.f,0.f,0.f};
  #pragma unroll
  for (int c=0;c<4;++c)
    #pragma unroll
    for (int r=0;r<4;++r) O[c][r] = 0.f;

  int rK0[4], rK1[4];
  #pragma unroll
  for (int c=0;c<4;++c){
    const int row = c*16 + l16;
    rK0[c] = row*64 + (((lg  ) ^ (row&7))<<3);
    rK1[c] = row*64 + (((4+lg) ^ (row&7))<<3);
  }

  // bias for current tile, prefetched one iteration ahead (w_h folded in)
  float bc[4][4];
  #pragma unroll
  for (int c=0;c<4;++c)
    #pragma unroll
    for (int r=0;r<4;++r)
      bc[c][r] = w_h * Bg[(size_t)r*2048 + c*16 + l16];

  // prologue: stage tile 0
  {
    bf16x8 k0v = *(const bf16x8*)Kg;
    bf16x8 v0v = *(const bf16x8*)Vg;
    *(bf16x8*)&Kl[0][wsw] = k0v;
    *(bf16x8*)&Vl[0][wsw] = v0v;
  }
  __syncthreads();

  int cur = 0;
  for (int kt=0; kt<nkt; ++kt){
    const int k0 = kt*64;
    const bool more = (kt+1 < nkt);
    bf16x8 kA, vA;
    float bn[4][4];
    if (more){
      kA = *(const bf16x8*)(Kg + (size_t)(k0+64)*64);
      vA = *(const bf16x8*)(Vg + (k0+64));
      #pragma unroll
      for (int c=0;c<4;++c)
        #pragma unroll
        for (int r=0;r<4;++r)
          bn[c][r] = w_h * Bg[(size_t)r*2048 + (k0+64) + c*16 + l16];
    }

    if (k0 <= qbase + 15){                 // wave-uniform skip of fully-masked tiles
      f32x4 S[4];
      #pragma unroll
      for (int c=0;c<4;++c)
        #pragma unroll
        for (int r=0;r<4;++r) S[c][r] = bc[c][r];

      __builtin_amdgcn_s_setprio(1);
      #pragma unroll
      for (int c=0;c<4;++c){
        bf16x8 kf0 = *(const bf16x8*)&Kl[cur][rK0[c]];
        bf16x8 kf1 = *(const bf16x8*)&Kl[cur][rK1[c]];
        S[c] = MFMA_BF16(qf0, kf0, S[c]);
        S[c] = MFMA_BF16(qf1, kf1, S[c]);
      }
      __builtin_amdgcn_s_setprio(0);

      #pragma unroll
      for (int c=0;c<4;++c){
        const int kg = k0 + c*16 + l16;
        #pragma unroll
        for (int r=0;r<4;++r){
          float s = S[c][r];
          if (kg > qg0+r) s = -1e30f;
          const float p = __expf(s - 4.0f);
          S[c][r] = p; l[r] += p;
        }
      }

      #pragma unroll
      for (int c=0;c<4;++c)
        #pragma unroll
        for (int r=0;r<4;++r)
          plds[wid][lg*4+r][c*16+l16] = (bf16)S[c][r];
      bf16x8 pf0 = *(const bf16x8*)&plds[wid][l16][lg*8];
      bf16x8 pf1 = *(const bf16x8*)&plds[wid][l16][lg*8+32];

      __builtin_amdgcn_s_setprio(1);
      #pragma unroll
      for (int c=0;c<4;++c){
        bf16x8 vf0 = *(const bf16x8*)&Vl[cur][rK0[c]];
        bf16x8 vf1 = *(const bf16x8*)&Vl[cur][rK1[c]];
        O[c] = MFMA_BF16(pf0, vf0, O[c]);
        O[c] = MFMA_BF16(pf1, vf1, O[c]);
      }
      __builtin_amdgcn_s_setprio(0);
    }

    if (more){
      *(bf16x8*)&Kl[cur^1][wsw] = kA;
      *(bf16x8*)&Vl[cur^1][wsw] = vA;
      #pragma unroll
      for (int c=0;c<4;++c)
        #pragma unroll
        for (int r=0;r<4;++r) bc[c][r] = bn[c][r];
    }
    __syncthreads();
    cur ^= (int)more;
  }

  #pragma unroll
  for (int r=0;r<4;++r){
    float v = l[r];
    v += __shfl_xor(v,1);
    v += __shfl_xor(v,2);
    v += __shfl_xor(v,4);
    v += __shfl_xor(v,8);
    l[r] = 1.0f / v;
  }
  #pragma unroll
  for (int c=0;c<4;++c)
    #pragma unroll
    for (int r=0;r<4;++r)
      attout[(size_t)(qg0+r)*2048 + h*64 + c*16 + l16] = (bf16)(O[c][r]*l[r]);
}

// ---------------- launcher ----------------
extern "C" void kernel_launch(void* const* d_in, const int* in_sizes, int n_in,
                              void* d_out, int out_size, void* d_ws, size_t ws_size,
                              hipStream_t stream){
  const float* x    = (const float*)d_in[0];
  const float* bias = (const float*)d_in[2];
  const float* mw   = (const float*)d_in[3];
  const float* Wq   = (const float*)d_in[4];
  const float* Wk   = (const float*)d_in[5];
  const float* Wv   = (const float*)d_in[6];
  const float* Wo   = (const float*)d_in[7];
  const float* ts   = (const float*)d_in[8];
  float* out = (float*)d_out;

  const size_t SZ = (size_t)2048*2048;
  bf16* base = (bf16*)d_ws;
  bf16* xb   = base;
  bf16* Wqb  = base + 1*SZ;
  bf16* Wkb  = base + 2*SZ;
  bf16* Wvb  = base + 3*SZ;
  bf16* Wob  = base + 4*SZ;
  bf16* Qsb  = base + 5*SZ;
  bf16* Ksb  = base + 6*SZ;
  bf16* Vtb  = base + 7*SZ;
  bf16* att  = base + 8*SZ;
  float* cosT = (float*)(base + 9*SZ);
  float* sinT = cosT + 2048*32;

  CvtArgs ca;
  ca.src[0]=x;  ca.src[1]=Wq;  ca.src[2]=Wk;  ca.src[3]=Wv;  ca.src[4]=Wo;
  ca.dst[0]=xb; ca.dst[1]=Wqb; ca.dst[2]=Wkb; ca.dst[3]=Wvb; ca.dst[4]=Wob;
  const int nb = (int)(SZ/8/256);
  cvt_rope_kernel<<<dim3(nb,6),256,0,stream>>>(ca, (int)SZ, cosT, sinT);
  gemm_qkv_kernel<<<dim3(16,16,3),256,0,stream>>>(xb, Wqb,Wkb,Wvb,
                                                  Qsb,Ksb,Vtb, cosT,sinT, mw,ts);
  attn_kernel<<<512,512,0,stream>>>(Qsb,Ksb,Vtb,bias,mw,att);
  gemm_out_kernel<<<dim3(32,16),256,0,stream>>>(att, Wob, out);
}